// Round 6
// baseline (271.193 us; speedup 1.0000x reference)
//
#include <hip/hip_runtime.h>

// Problem constants (fixed by setup_inputs in the reference)
#define T_TABLES 8
#define N_TAB    2097152          // indices per table (2^21)
#define B_TAB    8192             // batch per table (2^13); offsets len = B_TAB+1
#define NV_TAB   (N_TAB / 4)      // 524288 = 2^19 vec4 chunks per table
#define LOG2_N   21
#define LOG2_NV  19
#define LOG2_B   13

#define TOTAL_IDX (T_TABLES * N_TAB)       // 16777216
#define N_OFF_OUT (T_TABLES * B_TAB + 1)   // 65537
#define NVEC      (T_TABLES * NV_TAB)      // 4194304 vec4 chunks (indices region)
#define NW_CHUNKS (NVEC - 1)               // 4194303 aligned-store chunks (weights region, elems [3,16777215))

struct TablePtrs {
    const int*   idx[T_TABLES];
    const int*   off[T_TABLES];
    const float* wgt[T_TABLES];
};

typedef float __attribute__((ext_vector_type(4)))             float4v;
typedef int   __attribute__((ext_vector_type(4)))             int4v;
typedef float __attribute__((ext_vector_type(4), aligned(4))) float4u;  // 4B-aligned vec4 (split-load side)

__global__ __launch_bounds__(256)
void tbe_prep_kernel(TablePtrs p, float* __restrict__ out) {
    float* __restrict__ out_idx = out;                         // [0, 16777216)
    float* __restrict__ out_off = out + TOTAL_IDX;             // [.., +65537)
    float* __restrict__ out_w   = out + TOTAL_IDX + N_OFF_OUT; // [.., +16777216)  (odd base!)

    const int tid = blockIdx.x * blockDim.x + threadIdx.x;
    const int NT  = gridDim.x * blockDim.x;   // 2097152

    // ---- Region 1: indices int32 -> f32. Both sides 16B-aligned; nt both ways.
    {
        const int v0 = tid, v1 = tid + NT;   // NVEC == 2*NT, always in range
        const int t0 = v0 >> LOG2_NV, j0 = (v0 & (NV_TAB - 1)) << 2;
        const int t1 = v1 >> LOG2_NV, j1 = (v1 & (NV_TAB - 1)) << 2;
        const int4v ia = __builtin_nontemporal_load((const int4v*)(p.idx[t0] + j0));
        const int4v ib = __builtin_nontemporal_load((const int4v*)(p.idx[t1] + j1));
        float4v oa, ob;
        oa[0] = (float)ia[0]; oa[1] = (float)ia[1]; oa[2] = (float)ia[2]; oa[3] = (float)ia[3];
        ob[0] = (float)ib[0]; ob[1] = (float)ib[1]; ob[2] = (float)ib[2]; ob[3] = (float)ib[3];
        __builtin_nontemporal_store(oa, (float4v*)(out_idx + (v0 << 2)));
        __builtin_nontemporal_store(ob, (float4v*)(out_idx + (v1 << 2)));
    }

    // ---- Region 2: weights copy, shifted by 3 so STORES are 16B-aligned
    // (out_w+3 is at f32 index 16842756 % 4 == 0). Loads are the split side
    // (4B-aligned), left CACHED so wave-boundary shared lines hit L2.
    // Chunk c covers src/dst elements [3+4c, 7+4c); crosses a table boundary
    // iff (c+1) % NV_TAB == 0 (exactly 7 chunks) -> per-element slow path.
    {
        const int c0 = tid;
        #pragma unroll
        for (int u = 0; u < 2; ++u) {
            const int c = (u == 0) ? c0 : (c0 + NT);
            if (u == 1 && c >= NW_CHUNKS) break;   // only tid == NT-1 trips this
            const int s0 = 3 + (c << 2);
            float4v w;
            if (((c + 1) & (NV_TAB - 1)) != 0) {   // fast path: single table
                const int t = s0 >> LOG2_N, j = s0 & (N_TAB - 1);
                const float4u in = *(const float4u*)(p.wgt[t] + j);
                w[0] = in[0]; w[1] = in[1]; w[2] = in[2]; w[3] = in[3];
            } else {                               // 7 table-crossing chunks
                #pragma unroll
                for (int e = 0; e < 4; ++e) {
                    const int s = s0 + e;
                    w[e] = p.wgt[s >> LOG2_N][s & (N_TAB - 1)];
                }
            }
            __builtin_nontemporal_store(w, (float4v*)(out_w + 3 + (c << 2)));
        }
        if (tid == NT - 1) {  // head (elems 0..2) + tail (elem 16777215)
            out_w[0] = p.wgt[0][0];
            out_w[1] = p.wgt[0][1];
            out_w[2] = p.wgt[0][2];
            out_w[TOTAL_IDX - 1] = p.wgt[T_TABLES - 1][N_TAB - 1];
        }
    }

    // ---- Region 3: rebased offsets (65537 scalar f32 stores; exact, max 2^24)
    if (tid < T_TABLES * B_TAB) {
        const int t = tid >> LOG2_B;
        const int k = tid & (B_TAB - 1);
        out_off[tid] = (float)(p.off[t][k] + t * N_TAB);
    } else if (tid == T_TABLES * B_TAB) {
        out_off[tid] = (float)TOTAL_IDX;   // grand total = 16777216 (exact in f32)
    }
}

extern "C" void kernel_launch(void* const* d_in, const int* in_sizes, int n_in,
                              void* d_out, int out_size, void* d_ws, size_t ws_size,
                              hipStream_t stream) {
    // setup_inputs() builds its dict INSIDE the per-table loop, so d_in is
    // interleaved triplets: [indices_0, offsets_0, weights_0, indices_1, ...].
    // Detect layout defensively via in_sizes (offsets are the only 8193-sized
    // inputs): interleaved -> in_sizes[1]==8193; grouped -> in_sizes[8]==8193.
    TablePtrs p;
    const bool interleaved = (n_in >= 2 && in_sizes[1] == B_TAB + 1);
    for (int i = 0; i < T_TABLES; ++i) {
        if (interleaved) {
            p.idx[i] = (const int*)  d_in[3 * i + 0];
            p.off[i] = (const int*)  d_in[3 * i + 1];
            p.wgt[i] = (const float*)d_in[3 * i + 2];
        } else {
            p.idx[i] = (const int*)  d_in[i];
            p.off[i] = (const int*)  d_in[T_TABLES + i];
            p.wgt[i] = (const float*)d_in[2 * T_TABLES + i];
        }
    }
    float* out = (float*)d_out;

    // 8192 blocks x 256 threads = 2M threads: 2 vec4 chunks per thread per
    // region, fully unrolled. Pure-BW kernel; heavy oversubscription of 256 CUs.
    dim3 grid(8192), block(256);
    hipLaunchKernelGGL(tbe_prep_kernel, grid, block, 0, stream, p, out);
}